// Round 1
// baseline (281.983 us; speedup 1.0000x reference)
//
#include <hip/hip_runtime.h>

#define NN 100000
#define NE 800000
#define NPAD 100096  // 782*128, so GEMM row tiles never read OOB
#define OCT 12544    // 8*12544 = 100352 >= NN ; dst/OCT = XCD octant

typedef __attribute__((ext_vector_type(8))) __bf16 bf16x8;
typedef __attribute__((ext_vector_type(4))) float f32x4;

__device__ __forceinline__ uint f2bf(float f) {  // f32 -> bf16 bits (RNE), low 16
  uint u = __float_as_uint(f);
  return (u + 0x7fffu + ((u >> 16) & 1u)) >> 16;
}
__device__ __forceinline__ float bflo(uint u) { return __uint_as_float(u << 16); }
__device__ __forceinline__ float bfhi(uint u) { return __uint_as_float(u & 0xffff0000u); }

// ---------------- CSR build (XCD-partitioned hist/scatter) ----------------
__global__ __launch_bounds__(256) void k_hist(const int* __restrict__ dst,
                                              int* __restrict__ deg) {
  int xcd = blockIdx.x & 7, chunk = blockIdx.x >> 3;
  int e0 = chunk * 2048 + threadIdx.x;
#pragma unroll
  for (int i = 0; i < 8; ++i) {
    int e = e0 + i * 256;
    if (e < NE) {
      int d = dst[e];
      if (d / OCT == xcd) atomicAdd(&deg[d], 1);
    }
  }
}

__global__ void k_scan_partial(const int* __restrict__ deg, int* __restrict__ bsum, int N) {
  __shared__ int s[256];
  int b = blockIdx.x, t = threadIdx.x;
  int base = b * 1024 + t * 4;
  int v = 0;
#pragma unroll
  for (int i = 0; i < 4; ++i) { int idx = base + i; if (idx < N) v += deg[idx]; }
  s[t] = v; __syncthreads();
  for (int o = 128; o > 0; o >>= 1) { if (t < o) s[t] += s[t + o]; __syncthreads(); }
  if (t == 0) bsum[b] = s[0];
}

__global__ void k_scan_bsums(const int* __restrict__ bsum, int* __restrict__ bpre,
                             int* __restrict__ offsets, int NB, int N) {
  __shared__ int s[128];
  int t = threadIdx.x;
  int v = (t < NB) ? bsum[t] : 0;
  s[t] = v; __syncthreads();
  for (int o = 1; o < 128; o <<= 1) {
    int add = (t >= o) ? s[t - o] : 0;
    __syncthreads();
    s[t] += add;
    __syncthreads();
  }
  if (t < NB) bpre[t] = s[t] - v;
  if (t == NB - 1) offsets[N] = s[t];
}

__global__ void k_scan_final(const int* __restrict__ deg, const int* __restrict__ bpre,
                             int* __restrict__ offsets, int* __restrict__ cursor, int N) {
  __shared__ int s[256];
  int b = blockIdx.x, t = threadIdx.x;
  int base = b * 1024 + t * 4;
  int v[4];
#pragma unroll
  for (int i = 0; i < 4; ++i) { int idx = base + i; v[i] = (idx < N) ? deg[idx] : 0; }
  int tsum = v[0] + v[1] + v[2] + v[3];
  s[t] = tsum; __syncthreads();
  for (int o = 1; o < 256; o <<= 1) {
    int add = (t >= o) ? s[t - o] : 0;
    __syncthreads();
    s[t] += add;
    __syncthreads();
  }
  int run = s[t] - tsum + bpre[b];
#pragma unroll
  for (int i = 0; i < 4; ++i) {
    int idx = base + i;
    if (idx < N) { offsets[idx] = run; cursor[idx] = run; }
    run += v[i];
  }
}

__global__ __launch_bounds__(256) void k_scatter(const int* __restrict__ src,
                                                 const int* __restrict__ dst,
                                                 int* __restrict__ cursor,
                                                 int* __restrict__ csr_src) {
  int xcd = blockIdx.x & 7, chunk = blockIdx.x >> 3;
  int e0 = chunk * 2048 + threadIdx.x;
#pragma unroll
  for (int i = 0; i < 8; ++i) {
    int e = e0 + i * 256;
    if (e < NE) {
      int d = dst[e];
      if (d / OCT == xcd) {
        int pos = atomicAdd(&cursor[d], 1);
        csr_src[pos] = src[e];
      }
    }
  }
}

// ---------------- converts ----------------
__global__ void k_cvt_x(const float* __restrict__ x, ushort* __restrict__ xb) {
  int i = blockIdx.x * 256 + threadIdx.x;  // group of 4 floats
  if (i >= NPAD * 32) return;
  int row = i >> 5;
  float4 v = (row < NN) ? ((const float4*)x)[i] : make_float4(0.f, 0.f, 0.f, 0.f);
  uint2 o;
  o.x = f2bf(v.x) | (f2bf(v.y) << 16);
  o.y = f2bf(v.z) | (f2bf(v.w) << 16);
  ((uint2*)xb)[i] = o;
}

// transpose+convert all weights into [out][k] bf16
// layout: [Wr1t 16384][Wo1t 16384][Wr2t 32768][Wo2t 32768][Wt3 8192]
__global__ void k_cvt_w(const float* __restrict__ Wr1, const float* __restrict__ Wo1,
                        const float* __restrict__ Wr2, const float* __restrict__ Wo2,
                        const float* __restrict__ Wr3, const float* __restrict__ Wo3,
                        ushort* __restrict__ t) {
  int idx = blockIdx.x * 256 + threadIdx.x;
  if (idx >= 106496) return;
  float v;
  if (idx < 98304) {
    const float* W;
    int base, OUT;
    if (idx < 16384) { W = Wr1; base = 0; OUT = 128; }
    else if (idx < 32768) { W = Wo1; base = 16384; OUT = 128; }
    else if (idx < 65536) { W = Wr2; base = 32768; OUT = 256; }
    else { W = Wo2; base = 65536; OUT = 256; }
    int li = idx - base;
    int o = li >> 7, k = li & 127;
    v = W[(size_t)k * OUT + o];
  } else {
    int li = idx - 98304;  // [32][256]: o<16 -> Wrel3 col o ; o>=16 -> Wroot3 col o-16
    int o = li >> 8, k = li & 255;
    v = (o < 16) ? Wr3[(size_t)k * 16 + o] : Wo3[(size_t)k * 16 + (o - 16)];
  }
  t[idx] = (ushort)f2bf(v);
}

// ------- aggregation (128-dim bf16): one 16-lane subgroup per node, pipelined 4-batches ----
#define ACC8(q)                      \
  do {                               \
    acc[0] += bflo(q.x); acc[1] += bfhi(q.x); \
    acc[2] += bflo(q.y); acc[3] += bfhi(q.y); \
    acc[4] += bflo(q.z); acc[5] += bfhi(q.z); \
    acc[6] += bflo(q.w); acc[7] += bfhi(q.w); \
  } while (0)

__global__ __launch_bounds__(256) void k_aggbf(const ushort* __restrict__ X,
                                               const int* __restrict__ offsets,
                                               const int* __restrict__ csr,
                                               ushort* __restrict__ out) {
  int tid = threadIdx.x;
  int sg = tid >> 4, fl = tid & 15;
  int n = blockIdx.x * 16 + sg;
  if (n >= NN) return;
  int o0 = offsets[n], o1 = offsets[n + 1];
  const uint4* X4 = (const uint4*)X;
  float acc[8];
#pragma unroll
  for (int k = 0; k < 8; ++k) acc[k] = 0.f;
  int j = o0;
  if (j + 3 < o1) {
    uint4 q0 = X4[(size_t)csr[j] * 16 + fl];
    uint4 q1 = X4[(size_t)csr[j + 1] * 16 + fl];
    uint4 q2 = X4[(size_t)csr[j + 2] * 16 + fl];
    uint4 q3 = X4[(size_t)csr[j + 3] * 16 + fl];
    j += 4;
    while (j + 3 < o1) {
      uint4 p0 = X4[(size_t)csr[j] * 16 + fl];
      uint4 p1 = X4[(size_t)csr[j + 1] * 16 + fl];
      uint4 p2 = X4[(size_t)csr[j + 2] * 16 + fl];
      uint4 p3 = X4[(size_t)csr[j + 3] * 16 + fl];
      j += 4;
      ACC8(q0); ACC8(q1); ACC8(q2); ACC8(q3);
      q0 = p0; q1 = p1; q2 = p2; q3 = p3;
    }
    ACC8(q0); ACC8(q1); ACC8(q2); ACC8(q3);
  }
  for (; j < o1; ++j) {
    uint4 q = X4[(size_t)csr[j] * 16 + fl];
    ACC8(q);
  }
  uint4 o;
  o.x = f2bf(acc[0]) | (f2bf(acc[1]) << 16);
  o.y = f2bf(acc[2]) | (f2bf(acc[3]) << 16);
  o.z = f2bf(acc[4]) | (f2bf(acc[5]) << 16);
  o.w = f2bf(acc[6]) | (f2bf(acc[7]) << 16);
  ((uint4*)out)[(size_t)n * 16 + fl] = o;
}

// ---------------- MFMA dual GEMM: out = act(Aagg@Wrel + Aroot@Wroot + b), K=128 ----------------
// 128-row tiles, 16 rows/wave: the FULL K=128 of A and R fits in 32 VGPRs, so every
// global load (A regs + W via global_load_lds) is issued up-front and drained at ONE
// barrier — zero mid-loop global loads. acc shrinks to 32 AGPRs -> ~96 regs/wave,
// 2 blocks/CU resident (LDS 64KB): loads of one block overlap compute of the other.
// W swizzle widened to (row&15): read lanes have row&15==cl -> 16 distinct 16B slots
// -> bank-conflict-free (old &7 was a 4-way conflict, SQ_LDS_BANK_CONFLICT=1.6M).
__device__ __forceinline__ bf16x8 ldfrag(const ushort* base, int row, int kb) {
  int off = (row << 8) + (kb ^ ((row & 15) << 4));
  return *(const bf16x8*)((const char*)base + off);
}

template <int RELU>
__global__ __launch_bounds__(512, 4) void k_gemm_mfma(
    const ushort* __restrict__ Aagg, const ushort* __restrict__ Aroot,
    const ushort* __restrict__ Wrelt, const ushort* __restrict__ Wroott,
    const float* __restrict__ bias, ushort* __restrict__ out, int OUT) {
  __shared__ ushort sWr[128 * 128];
  __shared__ ushort sWo[128 * 128];
  int tid = threadIdx.x;
  int r0 = blockIdx.x * 128;
  int c0 = blockIdx.y * 128;

  int lane = tid & 63, wid = tid >> 6;
  int cl = lane & 15, hi = lane >> 4;
  const ushort* pa = Aagg + (size_t)(r0 + wid * 16 + cl) * 128 + hi * 8;
  const ushort* pr = Aroot + (size_t)(r0 + wid * 16 + cl) * 128 + hi * 8;

  // full-K A/R prefetch: 8 x 16B per lane, all in flight before the barrier
  bf16x8 A[4], R[4];
#pragma unroll
  for (int ks = 0; ks < 4; ++ks) {
    A[ks] = *(const bf16x8*)(pa + ks * 32);
    R[ks] = *(const bf16x8*)(pr + ks * 32);
  }

  const char* gw = (const char*)(Wrelt + (size_t)c0 * 128);
  const char* gu = (const char*)(Wroott + (size_t)c0 * 128);
#pragma unroll
  for (int i = 0; i < 4; ++i) {
    int L = (tid + i * 512) << 4;    // linear LDS byte in 32KB
    int row = L >> 8;
    int gb = L ^ ((row & 15) << 4);  // pre-swizzled global source (inverse involution)
    __builtin_amdgcn_global_load_lds((const __attribute__((address_space(1))) void*)(gw + gb),
                                     (__attribute__((address_space(3))) void*)((char*)sWr + L), 16, 0, 0);
    __builtin_amdgcn_global_load_lds((const __attribute__((address_space(1))) void*)(gu + gb),
                                     (__attribute__((address_space(3))) void*)((char*)sWo + L), 16, 0, 0);
  }
  __syncthreads();  // the ONE wait point: drains A-regs + W-LDS together

  f32x4 zero = {0.f, 0.f, 0.f, 0.f};
  f32x4 acc[8];
#pragma unroll
  for (int j = 0; j < 8; ++j) acc[j] = zero;

#pragma unroll
  for (int ks = 0; ks < 4; ++ks) {
    int kb = ks * 64 + hi * 16;
#pragma unroll
    for (int j = 0; j < 8; ++j) {
      bf16x8 wf = ldfrag(sWr, j * 16 + cl, kb);
      bf16x8 uf = ldfrag(sWo, j * 16 + cl, kb);
      acc[j] = __builtin_amdgcn_mfma_f32_16x16x32_bf16(A[ks], wf, acc[j], 0, 0, 0);
      acc[j] = __builtin_amdgcn_mfma_f32_16x16x32_bf16(R[ks], uf, acc[j], 0, 0, 0);
    }
  }

  // epilogue: C/D layout col=lane&15, row=(lane>>4)*4+reg (m89)
#pragma unroll
  for (int j = 0; j < 8; ++j) {
    int col = c0 + j * 16 + cl;
    float bv = bias[col];
#pragma unroll
    for (int reg = 0; reg < 4; ++reg) {
      int row = r0 + wid * 16 + hi * 4 + reg;
      if (row < NN) {
        float v = acc[j][reg] + bv;
        if (RELU) v = fmaxf(v, 0.f);
        out[(size_t)row * OUT + col] = (ushort)f2bf(v);
      }
    }
  }
}

// ---------------- layer 3 MFMA: y3b = h2@Wrel3 (bf16); z(d_out) = h2@Wroot3 + b3 ----------------
__global__ __launch_bounds__(512) void k_l3m(const ushort* __restrict__ h2,
                                             const ushort* __restrict__ Wt3,
                                             const float* __restrict__ bias,
                                             ushort* __restrict__ y3b, float* __restrict__ z) {
  int tid = threadIdx.x;
  int lane = tid & 63, wid = tid >> 6;
  int cl = lane & 15, hi = lane >> 4;
  size_t row0 = ((size_t)blockIdx.x * 8 + wid) * 16;
  bf16x8 b0[8], b1[8];
#pragma unroll
  for (int ks = 0; ks < 8; ++ks) {
    b0[ks] = *(const bf16x8*)(Wt3 + cl * 256 + ks * 32 + hi * 8);
    b1[ks] = *(const bf16x8*)(Wt3 + (16 + cl) * 256 + ks * 32 + hi * 8);
  }
  const ushort* arow = h2 + (row0 + cl) * 256 + hi * 8;
  f32x4 acc0 = {0.f, 0.f, 0.f, 0.f}, acc1 = {0.f, 0.f, 0.f, 0.f};
#pragma unroll
  for (int ks = 0; ks < 8; ++ks) {
    bf16x8 a = *(const bf16x8*)(arow + ks * 32);
    acc0 = __builtin_amdgcn_mfma_f32_16x16x32_bf16(a, b0[ks], acc0, 0, 0, 0);
    acc1 = __builtin_amdgcn_mfma_f32_16x16x32_bf16(a, b1[ks], acc1, 0, 0, 0);
  }
  float bv = bias[cl];
#pragma unroll
  for (int reg = 0; reg < 4; ++reg) {
    size_t row = row0 + hi * 4 + reg;
    if (row < NN) {
      y3b[row * 16 + cl] = (ushort)f2bf(acc0[reg]);
      z[row * 16 + cl] = acc1[reg] + bv;
    }
  }
}

// ---------------- fused: out = log_softmax(z + segsum(y3b[src])) ----------------
__global__ void k_agg16lsm(const int* __restrict__ offsets, const int* __restrict__ csr,
                           const ushort* __restrict__ y3b, float* __restrict__ out) {
  int t = blockIdx.x * 256 + threadIdx.x;  // (node, uint-pair) : 8 lanes per node
  if (t >= NN * 8) return;
  int n = t >> 3, g = t & 7;
  int o0 = offsets[n], o1 = offsets[n + 1];
  float a0 = 0.f, a1 = 0.f;
  const uint* Y = (const uint*)y3b;
  for (int j = o0; j < o1; ++j) {
    uint u = Y[(size_t)csr[j] * 8 + g];
    a0 += bflo(u); a1 += bfhi(u);
  }
  float v0 = out[n * 16 + g * 2] + a0;
  float v1 = out[n * 16 + g * 2 + 1] + a1;
  float m = fmaxf(v0, v1);
#pragma unroll
  for (int mask = 1; mask < 8; mask <<= 1) m = fmaxf(m, __shfl_xor(m, mask));
  float s = __expf(v0 - m) + __expf(v1 - m);
#pragma unroll
  for (int mask = 1; mask < 8; mask <<= 1) s += __shfl_xor(s, mask);
  float ls = __logf(s);
  out[n * 16 + g * 2] = v0 - m - ls;
  out[n * 16 + g * 2 + 1] = v1 - m - ls;
}

extern "C" void kernel_launch(void* const* d_in, const int* in_sizes, int n_in,
                              void* d_out, int out_size, void* d_ws, size_t ws_size,
                              hipStream_t stream) {
  const float* x = (const float*)d_in[0];
  const int* ei = (const int*)d_in[1];  // [2][NE]: row0=src, row1=dst
  const float* Wrel1 = (const float*)d_in[2];
  const float* Wroot1 = (const float*)d_in[3];
  const float* b1 = (const float*)d_in[4];
  const float* Wrel2 = (const float*)d_in[5];
  const float* Wroot2 = (const float*)d_in[6];
  const float* b2 = (const float*)d_in[7];
  const float* Wrel3 = (const float*)d_in[8];
  const float* Wroot3 = (const float*)d_in[9];
  const float* b3 = (const float*)d_in[10];
  float* out = (float*)d_out;

  char* ws = (char*)d_ws;
  size_t off = 0;
  auto alloc = [&](size_t bytes) {
    void* p = ws + off;
    off += (bytes + 255) / 256 * 256;
    return p;
  };
  int* deg = (int*)alloc((size_t)NN * 4);
  int* offsets = (int*)alloc((size_t)(NN + 1) * 4);
  int* cursor = (int*)alloc((size_t)NN * 4);
  int* bsum = (int*)alloc(128 * 4);
  int* bpre = (int*)alloc(128 * 4);
  int* csr = (int*)alloc((size_t)NE * 4);
  ushort* xb = (ushort*)alloc((size_t)NPAD * 128 * 2);
  ushort* aggb = (ushort*)alloc((size_t)NPAD * 128 * 2);
  ushort* h1b = (ushort*)alloc((size_t)NPAD * 128 * 2);
  ushort* h2b = (ushort*)alloc((size_t)NPAD * 256 * 2);
  ushort* y3b = (ushort*)alloc((size_t)NN * 16 * 2);
  ushort* wt = (ushort*)alloc((size_t)106496 * 2);
  ushort *Wr1t = wt, *Wo1t = wt + 16384, *Wr2t = wt + 32768, *Wo2t = wt + 65536;
  ushort* Wt3 = wt + 98304;

  const int* src = ei;
  const int* dst = ei + NE;

  // converts (independent of CSR)
  k_cvt_x<<<(NPAD * 32 + 255) / 256, 256, 0, stream>>>(x, xb);
  k_cvt_w<<<(106496 + 255) / 256, 256, 0, stream>>>(Wrel1, Wroot1, Wrel2, Wroot2, Wrel3,
                                                    Wroot3, wt);

  // CSR build (XCD-partitioned hist + scatter)
  hipMemsetAsync(deg, 0, (size_t)NN * 4, stream);
  int nchunk = (NE + 2047) / 2048;  // 391
  k_hist<<<8 * nchunk, 256, 0, stream>>>(dst, deg);
  int NB = (NN + 1023) / 1024;  // 98
  k_scan_partial<<<NB, 256, 0, stream>>>(deg, bsum, NN);
  k_scan_bsums<<<1, 128, 0, stream>>>(bsum, bpre, offsets, NB, NN);
  k_scan_final<<<NB, 256, 0, stream>>>(deg, bpre, offsets, cursor, NN);
  k_scatter<<<8 * nchunk, 256, 0, stream>>>(src, dst, cursor, csr);

  // layer 1: h1 = relu(agg(x)@Wr1 + x@Wo1 + b1)
  k_aggbf<<<(NN + 15) / 16, 256, 0, stream>>>(xb, offsets, csr, aggb);
  k_gemm_mfma<1><<<dim3(NPAD / 128, 1), 512, 0, stream>>>(aggb, xb, Wr1t, Wo1t, b1, h1b, 128);
  // layer 2: h2 = relu(agg(h1)@Wr2 + h1@Wo2 + b2)
  k_aggbf<<<(NN + 15) / 16, 256, 0, stream>>>(h1b, offsets, csr, aggb);
  k_gemm_mfma<1><<<dim3(NPAD / 128, 2), 512, 0, stream>>>(aggb, h1b, Wr2t, Wo2t, b2, h2b, 256);
  // layer 3
  k_l3m<<<NPAD / 128, 512, 0, stream>>>(h2b, Wt3, b3, y3b, out);
  k_agg16lsm<<<(NN * 8 + 255) / 256, 256, 0, stream>>>(offsets, csr, y3b, out);
}